// Round 9
// baseline (90.246 us; speedup 1.0000x reference)
//
#include <hip/hip_runtime.h>
#include <hip/hip_fp16.h>

#define NN 50000
#define NE 800000
#define D  64
#define NBUK 256
#define CHUNK (NE / NBUK)   // 3125 exactly
#define FS 68               // feat LDS stride (pad 64 -> 68)

typedef float __attribute__((ext_vector_type(4))) f32x4;

// ---------------------------------------------------------------------------
// block-wide exclusive scan of one int per thread (256 threads = 4 waves).
__device__ inline int block_exscan(int val, int tid) {
    __shared__ int wsum[4];
    int lane = tid & 63, w = tid >> 6;
    int v = val;
    #pragma unroll
    for (int d = 1; d < 64; d <<= 1) {
        int t = __shfl_up(v, d);
        if (lane >= d) v += t;
    }
    if (lane == 63) wsum[w] = v;
    __syncthreads();
    int base = 0;
    #pragma unroll
    for (int i = 0; i < 4; ++i) base += (i < w) ? wsum[i] : 0;
    __syncthreads();
    return base + v - val;   // exclusive
}

// ---------------------------------------------------------------------------
// pass A: per-block LDS histogram over buckets (col>>8). H is bucket-major.
__global__ __launch_bounds__(256) void k_hist(const int* __restrict__ col,
                                              int* __restrict__ H) {
    __shared__ int h[NBUK];
    const int tid = threadIdx.x, blk = blockIdx.x;
    h[tid] = 0;
    __syncthreads();
    const int base = blk * CHUNK;
    for (int i = tid; i < CHUNK; i += 256)
        atomicAdd(&h[col[base + i] >> 8], 1);
    __syncthreads();
    H[tid * NBUK + blk] = h[tid];
}

// pass B: scan H in place. Block j covers bucket j; bsum[j] = bucket total.
__global__ __launch_bounds__(256) void k_scanA(int* __restrict__ H,
                                               int* __restrict__ bsum) {
    const int tid = threadIdx.x, blk = blockIdx.x;
    const int i = blk * 256 + tid;
    int val = H[i];
    int ex = block_exscan(val, tid);
    H[i] = ex;
    if (tid == 255) bsum[blk] = ex + val;
}

// pass C: scatter edges into bucket segments as packed (row | (col&255)<<16)
__global__ __launch_bounds__(256) void k_bucket(const int* __restrict__ row,
                                                const int* __restrict__ col,
                                                const int* __restrict__ H,
                                                const int* __restrict__ bsum,
                                                unsigned int* __restrict__ packed) {
    __shared__ int base_l[NBUK];
    __shared__ int rank[NBUK];
    const int tid = threadIdx.x, blk = blockIdx.x;
    int ex = block_exscan(bsum[tid], tid);      // global bucket base
    base_l[tid] = ex + H[tid * NBUK + blk];     // + this block's chunk offset
    rank[tid] = 0;
    __syncthreads();
    const int base = blk * CHUNK;
    for (int i = tid; i < CHUNK; i += 256) {
        int c = col[base + i], r = row[base + i];
        int bk = c >> 8;
        int rk = atomicAdd(&rank[bk], 1);
        packed[base_l[bk] + rk] =
            (unsigned)(r & 0xFFFF) | ((unsigned)(c & 0xFF) << 16);
    }
}

// pass D: per-bucket CSR finalize: off/cnt per node + csr ushort rows.
__global__ __launch_bounds__(256) void k_csr(const unsigned int* __restrict__ packed,
                                             const int* __restrict__ bsum,
                                             int* __restrict__ off,
                                             int* __restrict__ cnt,
                                             unsigned short* __restrict__ csr) {
    __shared__ int exs[NBUK];
    __shared__ int ncnt[NBUK];
    __shared__ int nbase[NBUK];
    __shared__ int rk2[NBUK];
    const int tid = threadIdx.x, b = blockIdx.x;
    int ex = block_exscan(bsum[tid], tid);
    exs[tid] = ex;
    ncnt[tid] = 0;
    rk2[tid] = 0;
    __syncthreads();
    const int start = exs[b];
    const int size  = bsum[b];
    for (int i = tid; i < size; i += 256)
        atomicAdd(&ncnt[(packed[start + i] >> 16) & 0xFF], 1);
    __syncthreads();
    int v2  = ncnt[tid];
    int ex2 = block_exscan(v2, tid);
    const int node = b * NBUK + tid;
    off[node] = start + ex2;
    cnt[node] = v2;
    nbase[tid] = start + ex2;
    __syncthreads();
    for (int i = tid; i < size; i += 256) {
        unsigned u = packed[start + i];
        int ln = (u >> 16) & 0xFF;
        int rk = atomicAdd(&rk2[ln], 1);
        csr[nbase[ln] + rk] = (unsigned short)(u & 0xFFFF);
    }
}

// ---------------------------------------------------------------------------
// k_gemm: y{0,1}[r][d] = fp16( (feat[r] . W[:,d]) * rsqrt(cnt[r]+1) )
// column-split output: y0 = dims 0..31, y1 = dims 32..63 (each [NN,32] fp16)
__global__ __launch_bounds__(256) void k_gemm(const float* __restrict__ feat,
                                              const float* __restrict__ W,
                                              const int* __restrict__ cnt,
                                              __half* __restrict__ y0,
                                              __half* __restrict__ y1) {
    __shared__ float feat_lds[64 * FS];
    __shared__ float W_lds[D * D];

    const int tid   = threadIdx.x;
    const int rbase = blockIdx.x * 64;

    {
        const float4* W4  = reinterpret_cast<const float4*>(W);
        float4*       Wl4 = reinterpret_cast<float4*>(W_lds);
        for (int i = tid; i < D * D / 4; i += 256) Wl4[i] = W4[i];
    }
    {
        const int k0 = (tid & 15) * 4;
        #pragma unroll
        for (int it = 0; it < 4; ++it) {
            int r  = it * 16 + (tid >> 4);
            int gr = rbase + r;
            float4 v = make_float4(0.f, 0.f, 0.f, 0.f);
            if (gr < NN) v = *reinterpret_cast<const float4*>(&feat[gr * D + k0]);
            *reinterpret_cast<float4*>(&feat_lds[r * FS + k0]) = v;
        }
    }
    __syncthreads();

    const int tx = tid & 15;
    const int ty = tid >> 4;

    float acc[4][4] = {};

    #pragma unroll 8
    for (int k = 0; k < D; ++k) {
        float4 w = *reinterpret_cast<const float4*>(&W_lds[k * D + tx * 4]);
        float f0 = feat_lds[(ty * 4 + 0) * FS + k];
        float f1 = feat_lds[(ty * 4 + 1) * FS + k];
        float f2 = feat_lds[(ty * 4 + 2) * FS + k];
        float f3 = feat_lds[(ty * 4 + 3) * FS + k];
        acc[0][0] = fmaf(f0, w.x, acc[0][0]); acc[0][1] = fmaf(f0, w.y, acc[0][1]);
        acc[0][2] = fmaf(f0, w.z, acc[0][2]); acc[0][3] = fmaf(f0, w.w, acc[0][3]);
        acc[1][0] = fmaf(f1, w.x, acc[1][0]); acc[1][1] = fmaf(f1, w.y, acc[1][1]);
        acc[1][2] = fmaf(f1, w.z, acc[1][2]); acc[1][3] = fmaf(f1, w.w, acc[1][3]);
        acc[2][0] = fmaf(f2, w.x, acc[2][0]); acc[2][1] = fmaf(f2, w.y, acc[2][1]);
        acc[2][2] = fmaf(f2, w.z, acc[2][2]); acc[2][3] = fmaf(f2, w.w, acc[2][3]);
        acc[3][0] = fmaf(f3, w.x, acc[3][0]); acc[3][1] = fmaf(f3, w.y, acc[3][1]);
        acc[3][2] = fmaf(f3, w.z, acc[3][2]); acc[3][3] = fmaf(f3, w.w, acc[3][3]);
    }

    const int d0 = tx * 4;
    #pragma unroll
    for (int i = 0; i < 4; ++i) {
        int gr = rbase + ty * 4 + i;
        if (gr < NN) {
            float s = rsqrtf((float)cnt[gr] + 1.0f);
            __half2 h0 = __floats2half2_rn(acc[i][0] * s, acc[i][1] * s);
            __half2 h1 = __floats2half2_rn(acc[i][2] * s, acc[i][3] * s);
            union { __half2 h[2]; uint2 u; } p;
            p.h[0] = h0; p.h[1] = h1;
            __half* dst = (d0 < 32) ? &y0[gr * 32 + d0] : &y1[gr * 32 + (d0 - 32)];
            *reinterpret_cast<uint2*>(dst) = p.u;
        }
    }
}

// ---------------------------------------------------------------------------
// k_agg2: single-launch parity-split aggregation.
// block b: half = b&1 (under round-robin dispatch, each XCD sees ONE half ->
// per-XCD L2 hot set = 3.2 MB y-half, fits 4 MB). NT loads for csr/off/cnt
// and NT stores for out keep streams from evicting y.
// wave per (node,half); 8 groups x 8 lanes x uint2 (64B half-row per group);
// csr prefetched one-per-lane, broadcast via shfl in wave-uniform control flow.
__global__ __launch_bounds__(256) void k_agg2(const unsigned short* __restrict__ csr,
                                              const int* __restrict__ off,
                                              const int* __restrict__ cnt,
                                              const __half* __restrict__ y0,
                                              const __half* __restrict__ y1,
                                              const float* __restrict__ b,
                                              float* __restrict__ out) {
    const int lane = threadIdx.x & 63;
    const int grp  = lane >> 3;        // 0..7: edge slot within wave
    const int l2   = lane & 7;         // 8B column block within half-row
    const int half = blockIdx.x & 1;
    const int c    = (blockIdx.x >> 1) * 4 + (threadIdx.x >> 6);
    if (c >= NN) return;

    const __half* yh = half ? y1 : y0;
    const uint2*  y8 = reinterpret_cast<const uint2*>(yh);   // 4 halfs per uint2

    const int s = __builtin_nontemporal_load(&off[c]);
    const int n = __builtin_nontemporal_load(&cnt[c]);   // wave-uniform

    // prefetch up to 64 neighbor ids, one per lane (coalesced 2B NT loads)
    int pre = (lane < n) ? (int)__builtin_nontemporal_load(&csr[s + lane]) : 0;

    float acc[4] = {0.f, 0.f, 0.f, 0.f};

    auto addu = [&](uint2 u) {
        const __half2* h = reinterpret_cast<const __half2*>(&u);
        float2 f0 = __half22float2(h[0]);
        float2 f1 = __half22float2(h[1]);
        acc[0] += f0.x; acc[1] += f0.y; acc[2] += f1.x; acc[3] += f1.y;
    };

    if (grp == 0) addu(y8[c * 8 + l2]);   // self-loop

    const int iters = (n + 15) >> 4;      // wave-uniform trip count
    for (int m = 0; m < iters; ++m) {
        const int j  = grp + (m << 4);
        const int j2 = j + 8;
        int r1, r2;
        if (m < 4) {
            // j <= 55, j2 <= 63: in prefetch range; ALL 64 lanes active here
            r1 = __shfl(pre, j);
            r2 = __shfl(pre, j2);
        } else {
            r1 = (j  < n) ? (int)__builtin_nontemporal_load(&csr[s + j ]) : 0;
            r2 = (j2 < n) ? (int)__builtin_nontemporal_load(&csr[s + j2]) : 0;
        }
        if (j < n) {
            uint2 u1 = y8[r1 * 8 + l2];
            if (j2 < n) {
                uint2 u2 = y8[r2 * 8 + l2];
                addu(u1);
                addu(u2);
            } else {
                addu(u1);
            }
        }
    }

    // reduce across the 8 groups (butterfly over lane bits 3,4,5)
    #pragma unroll
    for (int m = 8; m <= 32; m <<= 1) {
        #pragma unroll
        for (int jj = 0; jj < 4; ++jj) acc[jj] += __shfl_xor(acc[jj], m);
    }

    if (grp == 0) {
        float sc = rsqrtf((float)n + 1.0f);
        float4 bb = reinterpret_cast<const float4*>(b)[half * 8 + l2];
        f32x4 o;
        o.x = acc[0] * sc + bb.x;
        o.y = acc[1] * sc + bb.y;
        o.z = acc[2] * sc + bb.z;
        o.w = acc[3] * sc + bb.w;
        f32x4* out4 = reinterpret_cast<f32x4*>(out);
        __builtin_nontemporal_store(o, &out4[c * 16 + half * 8 + l2]);
    }
}

// ---------------------------------------------------------------------------
extern "C" void kernel_launch(void* const* d_in, const int* in_sizes, int n_in,
                              void* d_out, int out_size, void* d_ws, size_t ws_size,
                              hipStream_t stream) {
    const float* feat = (const float*)d_in[0];   // [NN, D]
    const float* W    = (const float*)d_in[1];   // [D, D]
    const float* b    = (const float*)d_in[2];   // [D]
    const int*   ei   = (const int*)d_in[3];     // [2, NE]
    const int*   row  = ei;                      // sources
    const int*   col  = ei + NE;                 // targets

    float* out = (float*)d_out;                  // [NN, D]

    // workspace layout (~12 MB)
    int*            H      = (int*)d_ws;                      // [65536]
    int*            bsum   = H + 65536;                       // [256] (pad 1024)
    int*            cnt    = bsum + 1024;                     // [65536]
    int*            off    = cnt + 65536;                     // [65536]
    unsigned int*   packed = (unsigned int*)(off + 65536);    // [NE]
    unsigned short* csr    = (unsigned short*)(packed + NE);  // [NE]
    __half*         y0     = (__half*)(csr + NE);             // [NN*32]
    __half*         y1     = y0 + NN * 32;                    // [NN*32]

    k_hist  <<<NBUK, 256, 0, stream>>>(col, H);
    k_scanA <<<NBUK, 256, 0, stream>>>(H, bsum);
    k_bucket<<<NBUK, 256, 0, stream>>>(row, col, H, bsum, packed);
    k_csr   <<<NBUK, 256, 0, stream>>>(packed, bsum, off, cnt, csr);
    k_gemm  <<<(NN + 63) / 64, 256, 0, stream>>>(feat, W, cnt, y0, y1);
    k_agg2  <<<2 * ((NN + 3) / 4), 256, 0, stream>>>(csr, off, cnt, y0, y1, b, out);
}

// Round 10
// 57.705 us; speedup vs baseline: 1.5639x; 1.5639x over previous
//
#include <hip/hip_runtime.h>
#include <hip/hip_fp16.h>

#define NN 50000
#define NE 800000
#define D  64
#define NBUK 256
#define CHUNK (NE / NBUK)   // 3125 exactly
#define FS 68               // feat LDS stride (pad 64 -> 68)

typedef float __attribute__((ext_vector_type(4))) f32x4;

// ---------------------------------------------------------------------------
// block-wide exclusive scan of one int per thread (256 threads = 4 waves).
__device__ inline int block_exscan(int val, int tid) {
    __shared__ int wsum[4];
    int lane = tid & 63, w = tid >> 6;
    int v = val;
    #pragma unroll
    for (int d = 1; d < 64; d <<= 1) {
        int t = __shfl_up(v, d);
        if (lane >= d) v += t;
    }
    if (lane == 63) wsum[w] = v;
    __syncthreads();
    int base = 0;
    #pragma unroll
    for (int i = 0; i < 4; ++i) base += (i < w) ? wsum[i] : 0;
    __syncthreads();
    return base + v - val;   // exclusive
}

// ---------------------------------------------------------------------------
// pass A: per-block LDS histogram over buckets (col>>8). H is bucket-major.
__global__ __launch_bounds__(256) void k_hist(const int* __restrict__ col,
                                              int* __restrict__ H) {
    __shared__ int h[NBUK];
    const int tid = threadIdx.x, blk = blockIdx.x;
    h[tid] = 0;
    __syncthreads();
    const int base = blk * CHUNK;
    for (int i = tid; i < CHUNK; i += 256)
        atomicAdd(&h[col[base + i] >> 8], 1);
    __syncthreads();
    H[tid * NBUK + blk] = h[tid];
}

// pass B: scan H in place. Block j covers bucket j; bsum[j] = bucket total.
__global__ __launch_bounds__(256) void k_scanA(int* __restrict__ H,
                                               int* __restrict__ bsum) {
    const int tid = threadIdx.x, blk = blockIdx.x;
    const int i = blk * 256 + tid;
    int val = H[i];
    int ex = block_exscan(val, tid);
    H[i] = ex;
    if (tid == 255) bsum[blk] = ex + val;
}

// pass C: scatter edges into bucket segments as packed (row | (col&255)<<16)
__global__ __launch_bounds__(256) void k_bucket(const int* __restrict__ row,
                                                const int* __restrict__ col,
                                                const int* __restrict__ H,
                                                const int* __restrict__ bsum,
                                                unsigned int* __restrict__ packed) {
    __shared__ int base_l[NBUK];
    __shared__ int rank[NBUK];
    const int tid = threadIdx.x, blk = blockIdx.x;
    int ex = block_exscan(bsum[tid], tid);      // global bucket base
    base_l[tid] = ex + H[tid * NBUK + blk];     // + this block's chunk offset
    rank[tid] = 0;
    __syncthreads();
    const int base = blk * CHUNK;
    for (int i = tid; i < CHUNK; i += 256) {
        int c = col[base + i], r = row[base + i];
        int bk = c >> 8;
        int rk = atomicAdd(&rank[bk], 1);
        packed[base_l[bk] + rk] =
            (unsigned)(r & 0xFFFF) | ((unsigned)(c & 0xFF) << 16);
    }
}

// pass D: per-bucket CSR finalize: off/cnt per node + csr ushort rows.
__global__ __launch_bounds__(256) void k_csr(const unsigned int* __restrict__ packed,
                                             const int* __restrict__ bsum,
                                             int* __restrict__ off,
                                             int* __restrict__ cnt,
                                             unsigned short* __restrict__ csr) {
    __shared__ int exs[NBUK];
    __shared__ int ncnt[NBUK];
    __shared__ int nbase[NBUK];
    __shared__ int rk2[NBUK];
    const int tid = threadIdx.x, b = blockIdx.x;
    int ex = block_exscan(bsum[tid], tid);
    exs[tid] = ex;
    ncnt[tid] = 0;
    rk2[tid] = 0;
    __syncthreads();
    const int start = exs[b];
    const int size  = bsum[b];
    for (int i = tid; i < size; i += 256)
        atomicAdd(&ncnt[(packed[start + i] >> 16) & 0xFF], 1);
    __syncthreads();
    int v2  = ncnt[tid];
    int ex2 = block_exscan(v2, tid);
    const int node = b * NBUK + tid;
    off[node] = start + ex2;
    cnt[node] = v2;
    nbase[tid] = start + ex2;
    __syncthreads();
    for (int i = tid; i < size; i += 256) {
        unsigned u = packed[start + i];
        int ln = (u >> 16) & 0xFF;
        int rk = atomicAdd(&rk2[ln], 1);
        csr[nbase[ln] + rk] = (unsigned short)(u & 0xFFFF);
    }
}

// ---------------------------------------------------------------------------
// k_gemm: y[r][d] = fp16( (feat[r] . W[:,d]) * rsqrt(cnt[r]+1) )
__global__ __launch_bounds__(256) void k_gemm(const float* __restrict__ feat,
                                              const float* __restrict__ W,
                                              const int* __restrict__ cnt,
                                              __half* __restrict__ y) {
    __shared__ float feat_lds[64 * FS];
    __shared__ float W_lds[D * D];

    const int tid   = threadIdx.x;
    const int rbase = blockIdx.x * 64;

    {
        const float4* W4  = reinterpret_cast<const float4*>(W);
        float4*       Wl4 = reinterpret_cast<float4*>(W_lds);
        for (int i = tid; i < D * D / 4; i += 256) Wl4[i] = W4[i];
    }
    {
        const int k0 = (tid & 15) * 4;
        #pragma unroll
        for (int it = 0; it < 4; ++it) {
            int r  = it * 16 + (tid >> 4);
            int gr = rbase + r;
            float4 v = make_float4(0.f, 0.f, 0.f, 0.f);
            if (gr < NN) v = *reinterpret_cast<const float4*>(&feat[gr * D + k0]);
            *reinterpret_cast<float4*>(&feat_lds[r * FS + k0]) = v;
        }
    }
    __syncthreads();

    const int tx = tid & 15;
    const int ty = tid >> 4;

    float acc[4][4] = {};

    #pragma unroll 8
    for (int k = 0; k < D; ++k) {
        float4 w = *reinterpret_cast<const float4*>(&W_lds[k * D + tx * 4]);
        float f0 = feat_lds[(ty * 4 + 0) * FS + k];
        float f1 = feat_lds[(ty * 4 + 1) * FS + k];
        float f2 = feat_lds[(ty * 4 + 2) * FS + k];
        float f3 = feat_lds[(ty * 4 + 3) * FS + k];
        acc[0][0] = fmaf(f0, w.x, acc[0][0]); acc[0][1] = fmaf(f0, w.y, acc[0][1]);
        acc[0][2] = fmaf(f0, w.z, acc[0][2]); acc[0][3] = fmaf(f0, w.w, acc[0][3]);
        acc[1][0] = fmaf(f1, w.x, acc[1][0]); acc[1][1] = fmaf(f1, w.y, acc[1][1]);
        acc[1][2] = fmaf(f1, w.z, acc[1][2]); acc[1][3] = fmaf(f1, w.w, acc[1][3]);
        acc[2][0] = fmaf(f2, w.x, acc[2][0]); acc[2][1] = fmaf(f2, w.y, acc[2][1]);
        acc[2][2] = fmaf(f2, w.z, acc[2][2]); acc[2][3] = fmaf(f2, w.w, acc[2][3]);
        acc[3][0] = fmaf(f3, w.x, acc[3][0]); acc[3][1] = fmaf(f3, w.y, acc[3][1]);
        acc[3][2] = fmaf(f3, w.z, acc[3][2]); acc[3][3] = fmaf(f3, w.w, acc[3][3]);
    }

    #pragma unroll
    for (int i = 0; i < 4; ++i) {
        int gr = rbase + ty * 4 + i;
        if (gr < NN) {
            float s = rsqrtf((float)cnt[gr] + 1.0f);
            __half2 h0 = __floats2half2_rn(acc[i][0] * s, acc[i][1] * s);
            __half2 h1 = __floats2half2_rn(acc[i][2] * s, acc[i][3] * s);
            union { __half2 h[2]; uint2 u; } p;
            p.h[0] = h0; p.h[1] = h1;
            *reinterpret_cast<uint2*>(&y[gr * D + tx * 4]) = p.u;
        }
    }
}

// ---------------------------------------------------------------------------
// k_agg8: one 8-lane group per node, 8 nodes per wave.
//  - lane l8 of each group owns dims [8*l8, 8*l8+8) -> NO cross-lane reduction.
//  - group prefetches up to 32 edge ids (4 regs/lane); per 8-edge block all
//    8 row-gathers are issued unconditionally (safe index 0 when OOB) before
//    accumulation via mask-FMA -> 8 loads in flight, no divergent branches.
//  - shfl sources are group-internal; the per-block guard (8w < maxn) is
//    wave-uniform, so every ds_bpermute executes with all 64 lanes active.
__global__ __launch_bounds__(256) void k_agg8(const unsigned short* __restrict__ csr,
                                              const int* __restrict__ off,
                                              const int* __restrict__ cnt,
                                              const __half* __restrict__ y,
                                              const float* __restrict__ b,
                                              float* __restrict__ out) {
    const int lane = threadIdx.x & 63;
    const int g    = lane >> 3;        // group 0..7 = node slot within wave
    const int l8   = lane & 7;         // dim block within the node's row
    const int wave = blockIdx.x * 4 + (threadIdx.x >> 6);
    const int c    = wave * 8 + g;     // this group's node
    const bool valid = (c < NN);

    const uint4* y16 = reinterpret_cast<const uint4*>(y);

    const int s = valid ? off[c] : 0;
    const int n = valid ? cnt[c] : 0;   // group-uniform

    // wave max of n (n uniform within each 8-lane group)
    int maxn = n;
    maxn = max(maxn, __shfl_xor(maxn, 8));
    maxn = max(maxn, __shfl_xor(maxn, 16));
    maxn = max(maxn, __shfl_xor(maxn, 32));

    // prefetch up to 32 neighbor ids per group (lane w-th slot = edge l8+8w)
    int pre0 = (l8      < n) ? (int)csr[s + l8     ] : 0;
    int pre1 = (l8 + 8  < n) ? (int)csr[s + l8 + 8 ] : 0;
    int pre2 = (l8 + 16 < n) ? (int)csr[s + l8 + 16] : 0;
    int pre3 = (l8 + 24 < n) ? (int)csr[s + l8 + 24] : 0;

    float acc[8] = {0.f, 0.f, 0.f, 0.f, 0.f, 0.f, 0.f, 0.f};

    auto addm = [&](uint4 u, float m) {
        const __half2* h = reinterpret_cast<const __half2*>(&u);
        float2 f0 = __half22float2(h[0]);
        float2 f1 = __half22float2(h[1]);
        float2 f2 = __half22float2(h[2]);
        float2 f3 = __half22float2(h[3]);
        acc[0] = fmaf(m, f0.x, acc[0]); acc[1] = fmaf(m, f0.y, acc[1]);
        acc[2] = fmaf(m, f1.x, acc[2]); acc[3] = fmaf(m, f1.y, acc[3]);
        acc[4] = fmaf(m, f2.x, acc[4]); acc[5] = fmaf(m, f2.y, acc[5]);
        acc[6] = fmaf(m, f3.x, acc[6]); acc[7] = fmaf(m, f3.y, acc[7]);
    };

    // self-loop (safe index when invalid, masked to 0)
    {
        int cs = valid ? c : 0;
        uint4 u = y16[cs * 8 + l8];
        addm(u, valid ? 1.0f : 0.0f);
    }

    const int srcb = lane & 56;   // first lane of this group

    #pragma unroll
    for (int w = 0; w < 4; ++w) {
        if (w * 8 < maxn) {                       // wave-uniform guard
            const int pw = (w == 0) ? pre0 : (w == 1) ? pre1
                         : (w == 2) ? pre2 : pre3;
            uint4 u[8];
            float msk[8];
            #pragma unroll
            for (int e = 0; e < 8; ++e) {
                int r = __shfl(pw, srcb + e);     // all 64 lanes active
                u[e] = y16[r * 8 + l8];           // unconditional -> 8 in flight
                msk[e] = (w * 8 + e < n) ? 1.0f : 0.0f;
            }
            #pragma unroll
            for (int e = 0; e < 8; ++e) addm(u[e], msk[e]);
        }
    }

    // rare tail (deg > 32): group-divergent, no shfl -> safe
    for (int i = 32; i < n; ++i) {
        int r = (int)csr[s + i];                  // 8 lanes same addr
        addm(y16[r * 8 + l8], 1.0f);
    }

    if (valid) {
        float sc = rsqrtf((float)n + 1.0f);
        const float4* b4 = reinterpret_cast<const float4*>(b);
        float4 bb0 = b4[l8 * 2], bb1 = b4[l8 * 2 + 1];
        f32x4 o0, o1;
        o0.x = acc[0] * sc + bb0.x;  o0.y = acc[1] * sc + bb0.y;
        o0.z = acc[2] * sc + bb0.z;  o0.w = acc[3] * sc + bb0.w;
        o1.x = acc[4] * sc + bb1.x;  o1.y = acc[5] * sc + bb1.y;
        o1.z = acc[6] * sc + bb1.z;  o1.w = acc[7] * sc + bb1.w;
        f32x4* out4 = reinterpret_cast<f32x4*>(out);
        __builtin_nontemporal_store(o0, &out4[c * 16 + l8 * 2]);
        __builtin_nontemporal_store(o1, &out4[c * 16 + l8 * 2 + 1]);
    }
}

// ---------------------------------------------------------------------------
extern "C" void kernel_launch(void* const* d_in, const int* in_sizes, int n_in,
                              void* d_out, int out_size, void* d_ws, size_t ws_size,
                              hipStream_t stream) {
    const float* feat = (const float*)d_in[0];   // [NN, D]
    const float* W    = (const float*)d_in[1];   // [D, D]
    const float* b    = (const float*)d_in[2];   // [D]
    const int*   ei   = (const int*)d_in[3];     // [2, NE]
    const int*   row  = ei;                      // sources
    const int*   col  = ei + NE;                 // targets

    float* out = (float*)d_out;                  // [NN, D]

    // workspace layout (~12 MB)
    int*            H      = (int*)d_ws;                      // [65536]
    int*            bsum   = H + 65536;                       // [256] (pad 1024)
    int*            cnt    = bsum + 1024;                     // [65536]
    int*            off    = cnt + 65536;                     // [65536]
    unsigned int*   packed = (unsigned int*)(off + 65536);    // [NE]
    unsigned short* csr    = (unsigned short*)(packed + NE);  // [NE]
    __half*         y      = (__half*)(csr + NE);             // [NN*D], 16B-aligned

    k_hist  <<<NBUK, 256, 0, stream>>>(col, H);
    k_scanA <<<NBUK, 256, 0, stream>>>(H, bsum);
    k_bucket<<<NBUK, 256, 0, stream>>>(row, col, H, bsum, packed);
    k_csr   <<<NBUK, 256, 0, stream>>>(packed, bsum, off, cnt, csr);
    k_gemm  <<<(NN + 63) / 64, 256, 0, stream>>>(feat, W, cnt, y);
    k_agg8  <<<(NN + 31) / 32, 256, 0, stream>>>(csr, off, cnt, y, b, out);
}